// Round 1
// 372.468 us; speedup vs baseline: 1.0138x; 1.0138x over previous
//
#include <hip/hip_runtime.h>

// Sparse tensor product (e3nn 'uvu'): 128x0e+128x1o+128x2e (x) 1x0e+1x1o+1x2e -> 128x0e+128x1o+128x2e
// One thread per (z, u). CG coefficients computed at COMPILE TIME (constexpr port of the exact
// reference su2_cg / real<->complex basis change / Frobenius normalization, alpha folded in).
// Structural zeros (~2/3 of the 363 entries) are eliminated at compile time; nonzero values are
// inline literals -> no kernarg s_loads, ~2.4x fewer VALU ops per thread.

namespace {

constexpr int NPATH = 11;
constexpr int P_I1[NPATH] = {0,0,0,1,1,1,1,2,2,2,2};
constexpr int P_I2[NPATH] = {0,1,2,0,1,1,2,0,1,2,2};
constexpr int P_IO[NPATH] = {0,1,2,1,0,2,1,2,1,0,2};
constexpr int DIM_[3]  = {1,3,5};
constexpr int LOFF[3]  = {0,1,4};   // offsets of l-blocks inside a 9-float register set
constexpr int P_OFF[NPATH] = {0,1,10,35,44,53,98,143,168,213,238};
constexpr int CG_TOTAL = 363;

struct CGPack { float c[CG_TOTAL]; };

// ---------------- compile-time e3nn Wigner 3j (real basis) ----------------

constexpr int imax(int a, int b){ return a > b ? a : b; }
constexpr int imin(int a, int b){ return a < b ? a : b; }

constexpr double csqrt(double x){
  if (x <= 0.0) return 0.0;
  double r = (x > 1.0) ? x : 1.0;
  for (int i = 0; i < 64; ++i) r = 0.5 * (r + x / r);   // Newton, converges to ~1 ulp
  return r;
}

constexpr double fct(int n){ double r = 1.0; for (int i = 2; i <= n; ++i) r *= (double)i; return r; }

constexpr double su2_cg(int j1,int m1,int j2,int m2,int j3,int m3){
  if (m3 != m1 + m2) return 0.0;
  const int vmin = imax(imax(-j1 + j2 + m3, -j1 + m1), 0);
  const int vmax = imin(imin(j2 + j3 + m1, j3 - j1 + j2), j3 + m3);
  const double C = csqrt((2.0*j3 + 1.0) * fct(j3 + j1 - j2) * fct(j3 - j1 + j2) * fct(j1 + j2 - j3)
                         * fct(j3 + m3) * fct(j3 - m3)
                         / (fct(j1 + j2 + j3 + 1) * fct(j1 - m1) * fct(j1 + m1)
                            * fct(j2 - m2) * fct(j2 + m2)));
  double S = 0.0;
  for (int v = vmin; v <= vmax; ++v){
    const double t = fct(j2 + j3 + m1 - v) * fct(j1 - m1 + v)
                   / (fct(v) * fct(j3 - j1 + j2 - v) * fct(j3 + m3 - v) * fct(v + j1 - j2 - m3));
    S += (((v + j2 + m2) & 1) ? -1.0 : 1.0) * t;
  }
  return C * S;
}

struct cplx { double re; double im; };
constexpr cplx cmul(cplx a, cplx b){ return { a.re*b.re - a.im*b.im, a.re*b.im + a.im*b.re }; }
constexpr cplx cadd(cplx a, cplx b){ return { a.re + b.re, a.im + b.im }; }
constexpr cplx cconj(cplx a){ return { a.re, -a.im }; }

struct QMat { cplx q[5][5]; };

constexpr QMat q_mat(int l){
  QMat Q{};  // zero-init
  const double s = 1.0 / csqrt(2.0);
  for (int m = -l; m < 0; ++m){
    Q.q[l+m][l-m] = { s, 0.0 };          // col l+|m|
    Q.q[l+m][l+m] = { 0.0, -s };         // col l-|m|
  }
  Q.q[l][l] = { 1.0, 0.0 };
  for (int m = 1; m <= l; ++m){
    const double sg = (m & 1) ? -1.0 : 1.0;
    Q.q[l+m][l+m] = { sg * s, 0.0 };
    Q.q[l+m][l-m] = { 0.0, sg * s };
  }
  cplx ph = { 1.0, 0.0 };                 // (-i)^l phase
  for (int t = 0; t < l; ++t) ph = cmul(ph, cplx{0.0, -1.0});
  for (int a = 0; a < 5; ++a)
    for (int b = 0; b < 5; ++b)
      Q.q[a][b] = cmul(Q.q[a][b], ph);
  return Q;
}

struct W3J { float v[125]; };

constexpr W3J wigner3j(int l1, int l2, int l3, double scale){
  const int n1 = 2*l1+1, n2 = 2*l2+1, n3 = 2*l3+1;
  cplx C[5][5][5]{};
  for (int m1 = -l1; m1 <= l1; ++m1)
    for (int m2 = -l2; m2 <= l2; ++m2)
      for (int m3 = -l3; m3 <= l3; ++m3)
        C[l1+m1][l2+m2][l3+m3] = cplx{ su2_cg(l1, m1, l2, m2, l3, m3), 0.0 };
  const QMat Q1 = q_mat(l1), Q2 = q_mat(l2), Q3 = q_mat(l3);
  // out[a,b,c] = Re( sum_{i,k,n} Q1[i][a] * Q2[k][b] * conj(Q3[n][c]) * C[i][k][n] )
  // via sequential contraction (keeps constexpr step count tiny):
  cplx T1[5][5][5]{};
  for (int a = 0; a < n1; ++a)
    for (int k = 0; k < n2; ++k)
      for (int n = 0; n < n3; ++n){
        cplx s{0.0, 0.0};
        for (int i = 0; i < n1; ++i) s = cadd(s, cmul(Q1.q[i][a], C[i][k][n]));
        T1[a][k][n] = s;
      }
  cplx T2[5][5][5]{};
  for (int a = 0; a < n1; ++a)
    for (int b = 0; b < n2; ++b)
      for (int n = 0; n < n3; ++n){
        cplx s{0.0, 0.0};
        for (int k = 0; k < n2; ++k) s = cadd(s, cmul(Q2.q[k][b], T1[a][k][n]));
        T2[a][b][n] = s;
      }
  double R[5][5][5]{};
  double nrm = 0.0;
  for (int a = 0; a < n1; ++a)
    for (int b = 0; b < n2; ++b)
      for (int c = 0; c < n3; ++c){
        cplx s{0.0, 0.0};
        for (int n = 0; n < n3; ++n) s = cadd(s, cmul(cconj(Q3.q[n][c]), T2[a][b][n]));
        R[a][b][c] = s.re;
        nrm += s.re * s.re;
      }
  nrm = csqrt(nrm);
  W3J out{};
  for (int a = 0; a < n1; ++a)
    for (int b = 0; b < n2; ++b)
      for (int c = 0; c < n3; ++c){
        double v = scale * R[a][b][c] / nrm;
        if (v < 1e-6 && v > -1e-6) v = 0.0;   // snap structural zeros (residues ~1e-17)
        out.v[(a*n2 + b)*n3 + c] = (float)v;
      }
  return out;
}

constexpr CGPack build_pack(){
  CGPack p{};
  int npaths_to[3] = {0,0,0};
  for (int i = 0; i < NPATH; ++i) npaths_to[P_IO[i]]++;
  for (int i = 0; i < NPATH; ++i){
    const double alpha = csqrt((double)DIM_[P_IO[i]] / (double)npaths_to[P_IO[i]]);
    const W3J wj = wigner3j(P_I1[i], P_I2[i], P_IO[i], alpha);
    const int sz = DIM_[P_I1[i]] * DIM_[P_I2[i]] * DIM_[P_IO[i]];
    for (int t = 0; t < sz; ++t) p.c[P_OFF[i] + t] = wj.v[t];
  }
  return p;
}

constexpr CGPack CG = build_pack();   // forced compile-time evaluation

} // namespace

// ---------------- device kernel ----------------

__global__ __launch_bounds__(256) void tp_uvu_kernel(
    const float* __restrict__ x1, const float* __restrict__ x2,
    const float* __restrict__ w, float* __restrict__ out, int Z)
{
  const int u    = threadIdx.x & 127;       // mul index 0..127
  const int zloc = threadIdx.x >> 7;        // 0 or 1
  const int z    = blockIdx.x * 2 + zloc;
  const bool active = (z < Z);

  __shared__ float s_x2[2][9];
  if (active && u < 9) s_x2[zloc][u] = x2[(size_t)z * 9 + u];
  __syncthreads();
  if (!active) return;

  float xv2[9];
  #pragma unroll
  for (int j = 0; j < 9; ++j) xv2[j] = s_x2[zloc][j];

  const float* x1z = x1 + (size_t)z * 1152;
  float in1[9];
  in1[0] = x1z[u];
  #pragma unroll
  for (int i = 0; i < 3; ++i) in1[1+i] = x1z[128 + u*3 + i];
  #pragma unroll
  for (int i = 0; i < 5; ++i) in1[4+i] = x1z[512 + u*5 + i];

  float o[9];
  #pragma unroll
  for (int k = 0; k < 9; ++k) o[k] = 0.0f;

  #pragma unroll
  for (int p = 0; p < NPATH; ++p){
    const float wv = w[p * 128 + u];
    const int l1 = P_I1[p], l2 = P_I2[p], lo = P_IO[p];
    const int d1 = DIM_[l1], d2 = DIM_[l2], dd = DIM_[lo];
    const int b1 = LOFF[l1], b2 = LOFF[l2], bo = LOFF[lo];
    #pragma unroll
    for (int i = 0; i < d1; ++i){
      const float a = wv * in1[b1 + i];           // hoisted: d1 muls instead of d1*d2
      #pragma unroll
      for (int j = 0; j < d2; ++j){
        const float t = a * xv2[b2 + j];          // DCE'd when the whole k-row is zero
        #pragma unroll
        for (int k = 0; k < dd; ++k){
          const float cgv = CG.c[P_OFF[p] + (i*d2 + j)*dd + k];
          if (cgv != 0.0f)                        // compile-time constant after unroll+fold
            o[bo + k] = fmaf(t, cgv, o[bo + k]);
        }
      }
    }
  }

  float* oz = out + (size_t)z * 1152;
  oz[u] = o[0];
  #pragma unroll
  for (int k = 0; k < 3; ++k) oz[128 + u*3 + k] = o[1+k];
  #pragma unroll
  for (int k = 0; k < 5; ++k) oz[512 + u*5 + k] = o[4+k];
}

extern "C" void kernel_launch(void* const* d_in, const int* in_sizes, int n_in,
                              void* d_out, int out_size, void* d_ws, size_t ws_size,
                              hipStream_t stream)
{
  const float* x1 = (const float*)d_in[0];
  const float* x2 = (const float*)d_in[1];
  const float* w  = (const float*)d_in[2];
  float* out = (float*)d_out;
  const int Z = in_sizes[0] / 1152;

  const int zpb = 2;
  dim3 grid((Z + zpb - 1) / zpb), block(128 * zpb);
  hipLaunchKernelGGL(tp_uvu_kernel, grid, block, 0, stream,
                     x1, x2, w, out, Z);
}